// Round 1
// baseline (244.433 us; speedup 1.0000x reference)
//
#include <hip/hip_runtime.h>

#define N_NODES   20000
#define N_EDGES   640000
#define IN_DIM    128
#define HID_DIM   256
#define N_TYPES   4
#define N_ASPECTS 4096
#define NT4       (N_NODES * N_TYPES)   // 80000 CSR segments
#define NBUCK     157                   // dst buckets of 128 nodes
#define BCAP      5120                  // bucket capacity (mean 4096 + 16 sigma)
#define CHUNK     2560                  // edges per bucketA block (250 blocks exact)

typedef __bf16 v8bf __attribute__((ext_vector_type(8)));
typedef float  f32x4 __attribute__((ext_vector_type(4)));
typedef float  v2f   __attribute__((ext_vector_type(2)));

static __device__ __forceinline__ float bf2f(unsigned short u) {
    return __builtin_bit_cast(float, ((unsigned int)u) << 16);
}
static __device__ __forceinline__ float bflo(unsigned int u) {
    return __builtin_bit_cast(float, u << 16);
}
static __device__ __forceinline__ float bfhi(unsigned int u) {
    return __builtin_bit_cast(float, u & 0xffff0000u);
}
// f32 -> bf16 round-to-nearest-even (finite values)
static __device__ __forceinline__ unsigned short f2bf(float f) {
    unsigned int u = __builtin_bit_cast(unsigned int, f);
    u += 0x7fffu + ((u >> 16) & 1u);
    return (unsigned short)(u >> 16);
}

// async global->LDS, 16B per lane (m97 pattern: LDS dest linear in lane)
static __device__ __forceinline__ void gload16(const unsigned short* g, unsigned short* l) {
    __builtin_amdgcn_global_load_lds(
        (const __attribute__((address_space(1))) void*)g,
        (__attribute__((address_space(3))) void*)l,
        16, 0, 0);
}

// Per-block dtype detection: 1 KB sample of W_self1.
static __device__ __forceinline__ int local_flag(const unsigned short* w, int* red) {
    int tid = threadIdx.x;
    int c = 0;
    for (int i = tid; i < 1024; i += 256) {
        unsigned hb = (w[i] >> 8) & 0x7f;
        c += (hb >= 0x39 && hb <= 0x3D) ? 1 : 0;
    }
#pragma unroll
    for (int off = 32; off >= 1; off >>= 1) c += __shfl_down(c, off);
    if ((tid & 63) == 0) red[tid >> 6] = c;
    __syncthreads();
    int tot = red[0] + red[1] + red[2] + red[3];
    __syncthreads();
    return (tot >= 768) ? 1 : 0;
}

// ---------- fused: bucketA | convx(+fp8) | packW1 | packW2 | flag ----------
__global__ __launch_bounds__(256) void prepA_kernel(
        const void* __restrict__ x,
        const void* __restrict__ Ws1, const void* __restrict__ Wt1,
        const void* __restrict__ Ws2, const void* __restrict__ Wt2,
        const int* __restrict__ ei, const int* __restrict__ et,
        unsigned short* __restrict__ xc,
        unsigned int* __restrict__ xc8,
        unsigned short* __restrict__ WT1,
        unsigned short* __restrict__ WT2,
        int* __restrict__ bucket_cursor,
        unsigned int* __restrict__ breg,
        int* __restrict__ flag) {
    __shared__ __align__(16) char smem[14336];
    int b = blockIdx.x, tid = threadIdx.x;
    if (b < 250) {
        unsigned int* ord = (unsigned int*)smem;             // 2560*4 = 10240
        int* hist  = (int*)(smem + 10240);
        int* start = hist + NBUCK;
        int* cur   = start + NBUCK;
        int* gbase = cur + NBUCK;
        int* sbuf  = gbase + NBUCK;
        int e0 = b * CHUNK;
        for (int i = tid; i < NBUCK; i += 256) hist[i] = 0;
        __syncthreads();
        unsigned int pk[10];
        int bk[10];
#pragma unroll
        for (int r = 0; r < 10; r++) {
            int e = e0 + r * 256 + tid;
            int s = __builtin_nontemporal_load(ei + e);
            int d = __builtin_nontemporal_load(ei + N_EDGES + e);
            int t = __builtin_nontemporal_load(et + e);
            pk[r] = (unsigned int)s | ((unsigned int)t << 15) | ((unsigned int)d << 17);
            bk[r] = d >> 7;
            atomicAdd(&hist[bk[r]], 1);
        }
        __syncthreads();
        int v = (tid < NBUCK) ? hist[tid] : 0;
        sbuf[tid] = v;
        __syncthreads();
        for (int o = 1; o < 256; o <<= 1) {
            int t = (tid >= o) ? sbuf[tid - o] : 0;
            __syncthreads();
            sbuf[tid] += t;
            __syncthreads();
        }
        if (tid < NBUCK) { start[tid] = sbuf[tid] - v; cur[tid] = sbuf[tid] - v; }
        __syncthreads();
#pragma unroll
        for (int r = 0; r < 10; r++) {
            int p = atomicAdd(&cur[bk[r]], 1);
            ord[p] = pk[r];
        }
        __syncthreads();
        for (int bb = tid; bb < NBUCK; bb += 256)
            if (hist[bb] > 0) gbase[bb] = atomicAdd(bucket_cursor + bb, hist[bb]);
        __syncthreads();
        for (int p = tid; p < CHUNK; p += 256) {
            unsigned int e = ord[p];
            int bb = (int)(e >> 24);
            int gp = gbase[bb] + (p - start[bb]);
            if (gp < BCAP)
                __builtin_nontemporal_store(e, breg + (size_t)bb * BCAP + gp);
        }
    } else if (b < 1500) {               // convx: bf16 copy + fp8 shadow
        int bf = local_flag((const unsigned short*)Ws1, (int*)smem);
        int idx = (b - 250) * 256 + tid;  // 8-elem chunk
        float f[8];
        if (bf) {
            uint4 v = reinterpret_cast<const uint4*>(x)[idx];
            reinterpret_cast<uint4*>(xc)[idx] = v;
            f[0] = bflo(v.x); f[1] = bfhi(v.x);
            f[2] = bflo(v.y); f[3] = bfhi(v.y);
            f[4] = bflo(v.z); f[5] = bfhi(v.z);
            f[6] = bflo(v.w); f[7] = bfhi(v.w);
        } else {
            const float* xf = reinterpret_cast<const float*>(x) + (size_t)idx * 8;
            unsigned short r[8] __attribute__((aligned(16)));
#pragma unroll
            for (int j = 0; j < 8; j++) { f[j] = xf[j]; r[j] = f2bf(xf[j]); }
            reinterpret_cast<uint4*>(xc)[idx] = *reinterpret_cast<const uint4*>(r);
        }
        int lo = 0, hi = 0;
        lo = __builtin_amdgcn_cvt_pk_fp8_f32(f[0], f[1], lo, false);
        lo = __builtin_amdgcn_cvt_pk_fp8_f32(f[2], f[3], lo, true);
        hi = __builtin_amdgcn_cvt_pk_fp8_f32(f[4], f[5], hi, false);
        hi = __builtin_amdgcn_cvt_pk_fp8_f32(f[6], f[7], hi, true);
        xc8[idx * 2]     = (unsigned int)lo;
        xc8[idx * 2 + 1] = (unsigned int)hi;
    } else if (b < 2140) {               // packW1
        int bf = local_flag((const unsigned short*)Ws1, (int*)smem);
        int idx = (b - 1500) * 256 + tid;
        int n = idx / 640, k = idx - n * 640;
        const void* p = (k < 128) ? Ws1 : Wt1;
        size_t src = (k < 128) ? ((size_t)k * 256 + n) : ((size_t)(k - 128) * 256 + n);
        WT1[idx] = bf ? ((const unsigned short*)p)[src] : f2bf(((const float*)p)[src]);
    } else if (b < 3420) {               // packW2
        int bf = local_flag((const unsigned short*)Ws1, (int*)smem);
        int idx = (b - 2140) * 256 + tid;
        int n = idx / 1280, k = idx - n * 1280;
        const void* p = (k < 256) ? Ws2 : Wt2;
        size_t src = (k < 256) ? ((size_t)k * 256 + n) : ((size_t)(k - 256) * 256 + n);
        WT2[idx] = bf ? ((const unsigned short*)p)[src] : f2bf(((const float*)p)[src]);
    } else {
        int bf = local_flag((const unsigned short*)Ws1, (int*)smem);
        if (tid == 0) *flag = bf;
    }
}

// Pass B: per-bucket counting sort -> perm + offsets4 (parallel scans).
__global__ __launch_bounds__(256) void bucketB_kernel(
        const unsigned int* __restrict__ breg,
        const int* __restrict__ bucket_cursor,
        unsigned short* __restrict__ perm,
        int* __restrict__ offsets4) {
    __shared__ int cnt[512], off[512];
    __shared__ int buf[256], pscan[256];
    int b = blockIdx.x, tid = threadIdx.x;
    int cv = (tid < NBUCK) ? bucket_cursor[tid] : 0;
    if (cv > BCAP) cv = BCAP;
    buf[tid] = cv;
    __syncthreads();
    for (int o = 1; o < 256; o <<= 1) {
        int t = (tid >= o) ? buf[tid - o] : 0;
        __syncthreads();
        buf[tid] += t;
        __syncthreads();
    }
    int obase = (b > 0) ? buf[b - 1] : 0;
    if (b == 0 && tid == 0) offsets4[NT4] = buf[255];
    int Eb = bucket_cursor[b];
    if (Eb > BCAP) Eb = BCAP;
    for (int i = tid; i < 512; i += 256) cnt[i] = 0;
    __syncthreads();
    const unsigned int* reg = breg + (size_t)b * BCAP;
    for (int i = tid; i < Eb; i += 256) {
        unsigned int e = reg[i];
        int seg = (((e >> 17) & 127) << 2) | ((e >> 15) & 3);
        atomicAdd(&cnt[seg], 1);
    }
    __syncthreads();
    int pv = cnt[2 * tid] + cnt[2 * tid + 1];
    pscan[tid] = pv;
    __syncthreads();
    for (int o = 1; o < 256; o <<= 1) {
        int t = (tid >= o) ? pscan[tid - o] : 0;
        __syncthreads();
        pscan[tid] += t;
        __syncthreads();
    }
    int pexcl = pscan[tid] - pv;
    off[2 * tid]     = pexcl;
    off[2 * tid + 1] = pexcl + cnt[2 * tid];
    __syncthreads();
    for (int i = tid; i < 512; i += 256) {
        int node = b * 128 + (i >> 2);
        if (node < N_NODES) offsets4[node * 4 + (i & 3)] = obase + off[i];
    }
    __syncthreads();
    for (int i = tid; i < Eb; i += 256) {
        unsigned int e = reg[i];
        int seg = (((e >> 17) & 127) << 2) | ((e >> 15) & 3);
        int p = atomicAdd(&off[seg], 1);
        perm[obase + p] = (unsigned short)(e & 0x7fff);
    }
}

// ---------- typed aggregation: fp8 gather, f32 accumulate ------------------
// Subgroup of G = D/8 lanes, each loading uint2 (8 fp8); NSUB = 64/G
// subgroups gather independent edges, ILP4. Wave-uniform tail (R10 fix).
template <int D>
__global__ __launch_bounds__(256) void agg8_kernel(
        const unsigned int* __restrict__ F8,     // [N, D] fp8 (uint-chunked)
        const int* __restrict__ offs4,
        const unsigned short* __restrict__ perm,
        unsigned short* __restrict__ AG) {       // [N, 4*D] bf16
    constexpr int G = D / 8;                     // 16 (D=128) or 32 (D=256)
    constexpr int NSUB = 64 / G;                 // 4 or 2
    int wave = threadIdx.x >> 6, lane = threadIdx.x & 63;
    int sg = lane / G;
    int gl = lane - sg * G;
    for (int n = blockIdx.x * 4 + wave; n < N_NODES; n += gridDim.x * 4) {
        int o0 = offs4[n * 4];
        int o4 = offs4[n * 4 + 4];
        int deg = o4 - o0;
        float inv = 1.0f / (float)(deg > 1 ? deg : 1);
        int s0 = o0;
#pragma unroll
        for (int t = 0; t < 4; t++) {
            int s1 = offs4[n * 4 + t + 1];
            float a[8];
#pragma unroll
            for (int v = 0; v < 8; v++) a[v] = 0.f;
            int j = s0;
            while (j < s1) {
                int m = s1 - j;
                if (m > 64) m = 64;
                int pw = (int)perm[j + ((lane < m) ? lane : 0)];
                int nfull = (m / (NSUB * 4)) * (NSUB * 4);
                for (int base = 0; base < nfull; base += NSUB * 4) {
                    uint2 x[4];
#pragma unroll
                    for (int l = 0; l < 4; l++) {
                        int src = __shfl(pw, base + sg * 4 + l);
                        x[l] = *reinterpret_cast<const uint2*>(F8 + (size_t)src * (D / 4) + gl * 2);
                    }
#pragma unroll
                    for (int l = 0; l < 4; l++) {
                        v2f p0 = __builtin_amdgcn_cvt_pk_f32_fp8((int)x[l].x, false);
                        v2f p1 = __builtin_amdgcn_cvt_pk_f32_fp8((int)x[l].x, true);
                        v2f p2 = __builtin_amdgcn_cvt_pk_f32_fp8((int)x[l].y, false);
                        v2f p3 = __builtin_amdgcn_cvt_pk_f32_fp8((int)x[l].y, true);
                        a[0] += p0.x; a[1] += p0.y;
                        a[2] += p1.x; a[3] += p1.y;
                        a[4] += p2.x; a[5] += p2.y;
                        a[6] += p3.x; a[7] += p3.y;
                    }
                }
                for (int k = nfull; k < m; k += NSUB) {
                    int e = k + sg;
                    int valid = (e < m);
                    int idx = valid ? e : (m - 1);
                    int src = __shfl(pw, idx);
                    uint2 x = *reinterpret_cast<const uint2*>(F8 + (size_t)src * (D / 4) + gl * 2);
                    unsigned msk = valid ? 0xffffffffu : 0u;  // fp8 0x00 == +0.0
                    x.x &= msk; x.y &= msk;
                    v2f p0 = __builtin_amdgcn_cvt_pk_f32_fp8((int)x.x, false);
                    v2f p1 = __builtin_amdgcn_cvt_pk_f32_fp8((int)x.x, true);
                    v2f p2 = __builtin_amdgcn_cvt_pk_f32_fp8((int)x.y, false);
                    v2f p3 = __builtin_amdgcn_cvt_pk_f32_fp8((int)x.y, true);
                    a[0] += p0.x; a[1] += p0.y;
                    a[2] += p1.x; a[3] += p1.y;
                    a[4] += p2.x; a[5] += p2.y;
                    a[6] += p3.x; a[7] += p3.y;
                }
                j += m;
            }
#pragma unroll
            for (int v = 0; v < 8; v++) {
                float s = a[v];
                s += __shfl_xor(s, G);
                if (NSUB == 4) s += __shfl_xor(s, 2 * G);
                a[v] = s * inv;
            }
            if (sg == 0) {
                unsigned short r[8] __attribute__((aligned(16)));
#pragma unroll
                for (int v = 0; v < 8; v++) r[v] = f2bf(a[v]);
                *reinterpret_cast<uint4*>(AG + (size_t)n * (4 * D) + t * D + gl * 8) =
                    *reinterpret_cast<const uint4*>(r);
            }
            s0 = s1;
        }
    }
}

// ---------- MFMA GEMM: C[M,256] = [X | AG] @ WT^T + bias -------------------
// R15: m97 structure — 128x128 tile, BK=64, 4 waves (2x2), 4x4 16x16x32
// fragments per wave, global_load_lds width-16 staging into LINEAR LDS
// (T2 swizzle is measured-NULL on 2-phase structures; m97 ate the read
// conflict and still hit 874 TF). A-row tail handled by source CLAMP
// (clamped rows only feed their own never-stored C rows). Grid 320 blocks:
// bijective pairing so both N-tiles of an M-tile land on the same XCD
// (b%8 preserved), A-panel fetched once per pair.
template <int D>
__global__ __launch_bounds__(256) void gemm_kernel(
        const unsigned short* __restrict__ X,
        const unsigned short* __restrict__ AG,
        const unsigned short* __restrict__ BT,
        const void* __restrict__ bias,
        const int* __restrict__ flagp,
        unsigned short* __restrict__ C,
        unsigned char* __restrict__ C8,          // fp8 shadow (or nullptr)
        int M, int relu) {
    constexpr int K = 5 * D;
    __shared__ __align__(16) unsigned short As[128 * 64];
    __shared__ __align__(16) unsigned short Bs[128 * 64];
    int b = blockIdx.x;
    int mt = (b >> 4) * 8 + (b & 7);   // [0,160)
    int nt = (b >> 3) & 1;
    int mtiles = (M + 127) >> 7;
    if (mt >= mtiles) return;
    int m0 = mt * 128;
    int n0 = nt * 128;
    int tid  = threadIdx.x;
    int wave = tid >> 6, lane = tid & 63;
    int wm = wave >> 1, wn = wave & 1;        // each wave: 64x64 output
    int quad = lane >> 4, l16 = lane & 15;

    f32x4 acc[4][4];
#pragma unroll
    for (int i = 0; i < 4; i++)
#pragma unroll
        for (int j = 0; j < 4; j++) acc[i][j] = (f32x4){0.f, 0.f, 0.f, 0.f};

    for (int k0 = 0; k0 < K; k0 += 64) {
        const unsigned short* abase = (k0 < D) ? X : AG;
        int rs  = (k0 < D) ? D : 4 * D;
        int col = (k0 < D) ? k0 : (k0 - D);
        // A tile: 128 rows x 64 cols bf16 = 1024 x 16B chunks; 4 per thread
#pragma unroll
        for (int p = 0; p < 4; p++) {
            int c   = p * 256 + tid;
            int row = c >> 3;
            int c8  = c & 7;
            int gr  = m0 + row;
            if (gr >= M) gr = M - 1;          // clamp: affects only rows >= M
            gload16(abase + (size_t)gr * rs + col + c8 * 8, &As[c * 8]);
        }
#pragma unroll
        for (int p = 0; p < 4; p++) {
            int c   = p * 256 + tid;
            int row = c >> 3;
            int c8  = c & 7;
            gload16(BT + (size_t)(n0 + row) * K + k0 + c8 * 8, &Bs[c * 8]);
        }
        __syncthreads();
#pragma unroll
        for (int ks = 0; ks < 2; ks++) {
            v8bf af[4], bfr[4];
#pragma unroll
            for (int i = 0; i < 4; i++)
                af[i] = *reinterpret_cast<const v8bf*>(
                    &As[(wm * 64 + i * 16 + l16) * 64 + ks * 32 + quad * 8]);
#pragma unroll
            for (int j = 0; j < 4; j++)
                bfr[j] = *reinterpret_cast<const v8bf*>(
                    &Bs[(wn * 64 + j * 16 + l16) * 64 + ks * 32 + quad * 8]);
#pragma unroll
            for (int i = 0; i < 4; i++)
#pragma unroll
                for (int j = 0; j < 4; j++)
                    acc[i][j] = __builtin_amdgcn_mfma_f32_16x16x32_bf16(af[i], bfr[j], acc[i][j], 0, 0, 0);
        }
        __syncthreads();
    }
    int bf = *flagp;
#pragma unroll
    for (int i = 0; i < 4; i++) {
#pragma unroll
        for (int j = 0; j < 4; j++) {
            int col = n0 + wn * 64 + j * 16 + l16;
            float bv = bf ? bf2f(((const unsigned short*)bias)[col])
                          : ((const float*)bias)[col];
#pragma unroll
            for (int r = 0; r < 4; r++) {
                int row = m0 + wm * 64 + i * 16 + quad * 4 + r;
                if (row < M) {
                    float v = acc[i][j][r] + bv;
                    if (relu) v = fmaxf(v, 0.0f);
                    C[(size_t)row * 256 + col] = f2bf(v);
                    if (C8) {
                        int pk = __builtin_amdgcn_cvt_pk_fp8_f32(v, v, 0, false);
                        C8[(size_t)row * 256 + col] = (unsigned char)(pk & 0xff);
                    }
                }
            }
        }
    }
}

// ---------- classifier head ------------------------------------------------
__global__ void cls_kernel(const unsigned short* __restrict__ h2,
                           const int* __restrict__ aidx,
                           const void* __restrict__ Wc,
                           const void* __restrict__ bc,
                           const int* __restrict__ flagp,
                           void* __restrict__ out) {
    int lin = blockIdx.x * blockDim.x + threadIdx.x;
    int a = lin >> 6, lane = lin & 63;
    if (a >= N_ASPECTS) return;
    int bf = *flagp;
    int node = aidx[a];
    uint2 v = *reinterpret_cast<const uint2*>(h2 + (size_t)node * 256 + lane * 4);
    float hv[4] = {bflo(v.x), bfhi(v.x), bflo(v.y), bfhi(v.y)};
    float a0 = 0.f, a1 = 0.f, a2 = 0.f;
#pragma unroll
    for (int r = 0; r < 4; r++) {
        int k = lane * 4 + r;
        float w0 = bf ? bf2f(((const unsigned short*)Wc)[k * 3 + 0]) : ((const float*)Wc)[k * 3 + 0];
        float w1 = bf ? bf2f(((const unsigned short*)Wc)[k * 3 + 1]) : ((const float*)Wc)[k * 3 + 1];
        float w2 = bf ? bf2f(((const unsigned short*)Wc)[k * 3 + 2]) : ((const float*)Wc)[k * 3 + 2];
        a0 += hv[r] * w0;
        a1 += hv[r] * w1;
        a2 += hv[r] * w2;
    }
#pragma unroll
    for (int off = 32; off >= 1; off >>= 1) {
        a0 += __shfl_down(a0, off);
        a1 += __shfl_down(a1, off);
        a2 += __shfl_down(a2, off);
    }
    if (lane == 0) {
        float b0 = bf ? bf2f(((const unsigned short*)bc)[0]) : ((const float*)bc)[0];
        float b1 = bf ? bf2f(((const unsigned short*)bc)[1]) : ((const float*)bc)[1];
        float b2 = bf ? bf2f(((const unsigned short*)bc)[2]) : ((const float*)bc)[2];
        if (bf) {
            unsigned short* o = (unsigned short*)out;
            o[a * 3 + 0] = f2bf(a0 + b0);
            o[a * 3 + 1] = f2bf(a1 + b1);
            o[a * 3 + 2] = f2bf(a2 + b2);
        } else {
            float* o = (float*)out;
            o[a * 3 + 0] = a0 + b0;
            o[a * 3 + 1] = a1 + b1;
            o[a * 3 + 2] = a2 + b2;
        }
    }
}

extern "C" void kernel_launch(void* const* d_in, const int* in_sizes, int n_in,
                              void* d_out, int out_size, void* d_ws, size_t ws_size,
                              hipStream_t stream) {
    const void* x   = d_in[0];
    const void* Wt1 = d_in[1];
    const void* Ws1 = d_in[2];
    const void* b1  = d_in[3];
    const void* Wt2 = d_in[4];
    const void* Ws2 = d_in[5];
    const void* b2  = d_in[6];
    const void* Wc  = d_in[7];
    const void* bc  = d_in[8];
    const int* ei = (const int*)d_in[9];
    const int* et = (const int*)d_in[10];
    const int* ai = (const int*)d_in[11];

    char* ws = (char*)d_ws;
    size_t off = 0;
    auto alloc = [&](size_t bytes) {
        void* p = ws + off;
        off += (bytes + 255) & ~(size_t)255;
        return p;
    };
    int*            flag          = (int*)alloc(4);
    int*            bucket_cursor = (int*)alloc((size_t)NBUCK * 4);
    int*            offsets4      = (int*)alloc((size_t)(NT4 + 1) * 4);
    unsigned int*   breg          = (unsigned int*)alloc((size_t)NBUCK * BCAP * 4); // 3.2 MB
    unsigned short* perm          = (unsigned short*)alloc((size_t)N_EDGES * 2);
    unsigned short* xc            = (unsigned short*)alloc((size_t)N_NODES * IN_DIM * 2);
    unsigned int*   xc8           = (unsigned int*)alloc((size_t)N_NODES * IN_DIM);    // 2.6 MB fp8
    unsigned short* AG            = (unsigned short*)alloc((size_t)N_NODES * 4 * HID_DIM * 2);
    unsigned short* h             = (unsigned short*)alloc((size_t)N_NODES * HID_DIM * 2);
    unsigned char*  h8            = (unsigned char*)alloc((size_t)N_NODES * HID_DIM);  // 5.1 MB fp8
    unsigned short* h2            = (unsigned short*)alloc((size_t)N_NODES * HID_DIM * 2);
    unsigned short* WT1           = (unsigned short*)alloc((size_t)640 * 256 * 2);
    unsigned short* WT2           = (unsigned short*)alloc((size_t)1280 * 256 * 2);
    // total ~60 MB

    hipMemsetAsync(bucket_cursor, 0, (size_t)NBUCK * 4, stream);
    prepA_kernel<<<3421, 256, 0, stream>>>(x, Ws1, Wt1, Ws2, Wt2, ei, et,
                                           xc, xc8, WT1, WT2, bucket_cursor, breg, flag);
    bucketB_kernel<<<NBUCK, 256, 0, stream>>>(breg, bucket_cursor, perm, offsets4);

    // Layer 1 (fp8 gather on x; self-term X stays bf16)
    agg8_kernel<IN_DIM><<<4096, 256, 0, stream>>>(xc8, offsets4, perm, AG);
    gemm_kernel<IN_DIM><<<320, 256, 0, stream>>>(xc, AG, WT1, b1, flag, h, h8, N_NODES, 1);
    // Layer 2 (fp8 shadow emitted by gemm1's epilogue)
    agg8_kernel<HID_DIM><<<4096, 256, 0, stream>>>((const unsigned int*)h8, offsets4, perm, AG);
    gemm_kernel<HID_DIM><<<320, 256, 0, stream>>>(h, AG, WT2, b2, flag, h2, nullptr, N_NODES, 0);
    // Head
    cls_kernel<<<(N_ASPECTS * 64) / 256, 256, 0, stream>>>(h2, ai, Wc, bc, flag, d_out);
}

// Round 2
// 241.342 us; speedup vs baseline: 1.0128x; 1.0128x over previous
//
#include <hip/hip_runtime.h>

#define N_NODES   20000
#define N_EDGES   640000
#define IN_DIM    128
#define HID_DIM   256
#define N_TYPES   4
#define N_ASPECTS 4096
#define NT4       (N_NODES * N_TYPES)   // 80000 CSR segments
#define NBUCK     157                   // dst buckets of 128 nodes
#define BCAP      5120                  // bucket capacity (mean 4096 + 16 sigma)
#define CHUNK     2560                  // edges per bucketA block (250 blocks exact)

typedef __bf16 v8bf __attribute__((ext_vector_type(8)));
typedef float  f32x4 __attribute__((ext_vector_type(4)));
typedef float  v2f   __attribute__((ext_vector_type(2)));

static __device__ __forceinline__ float bf2f(unsigned short u) {
    return __builtin_bit_cast(float, ((unsigned int)u) << 16);
}
static __device__ __forceinline__ float bflo(unsigned int u) {
    return __builtin_bit_cast(float, u << 16);
}
static __device__ __forceinline__ float bfhi(unsigned int u) {
    return __builtin_bit_cast(float, u & 0xffff0000u);
}
// f32 -> bf16 round-to-nearest-even (finite values)
static __device__ __forceinline__ unsigned short f2bf(float f) {
    unsigned int u = __builtin_bit_cast(unsigned int, f);
    u += 0x7fffu + ((u >> 16) & 1u);
    return (unsigned short)(u >> 16);
}

// async global->LDS, 16B per lane (m97 pattern: LDS dest linear in lane)
static __device__ __forceinline__ void gload16(const unsigned short* g, unsigned short* l) {
    __builtin_amdgcn_global_load_lds(
        (const __attribute__((address_space(1))) void*)g,
        (__attribute__((address_space(3))) void*)l,
        16, 0, 0);
}

// Per-block dtype detection: 1 KB sample of W_self1.
static __device__ __forceinline__ int local_flag(const unsigned short* w, int* red) {
    int tid = threadIdx.x;
    int c = 0;
    for (int i = tid; i < 1024; i += 256) {
        unsigned hb = (w[i] >> 8) & 0x7f;
        c += (hb >= 0x39 && hb <= 0x3D) ? 1 : 0;
    }
#pragma unroll
    for (int off = 32; off >= 1; off >>= 1) c += __shfl_down(c, off);
    if ((tid & 63) == 0) red[tid >> 6] = c;
    __syncthreads();
    int tot = red[0] + red[1] + red[2] + red[3];
    __syncthreads();
    return (tot >= 768) ? 1 : 0;
}

// ---------- fused: bucketA | convx(+fp8) | packW1 | packW2 | flag ----------
__global__ __launch_bounds__(256) void prepA_kernel(
        const void* __restrict__ x,
        const void* __restrict__ Ws1, const void* __restrict__ Wt1,
        const void* __restrict__ Ws2, const void* __restrict__ Wt2,
        const int* __restrict__ ei, const int* __restrict__ et,
        unsigned short* __restrict__ xc,
        unsigned int* __restrict__ xc8,
        unsigned short* __restrict__ WT1,
        unsigned short* __restrict__ WT2,
        int* __restrict__ bucket_cursor,
        unsigned int* __restrict__ breg,
        int* __restrict__ flag) {
    __shared__ __align__(16) char smem[14336];
    int b = blockIdx.x, tid = threadIdx.x;
    if (b < 250) {
        unsigned int* ord = (unsigned int*)smem;             // 2560*4 = 10240
        int* hist  = (int*)(smem + 10240);
        int* start = hist + NBUCK;
        int* cur   = start + NBUCK;
        int* gbase = cur + NBUCK;
        int* sbuf  = gbase + NBUCK;
        int e0 = b * CHUNK;
        for (int i = tid; i < NBUCK; i += 256) hist[i] = 0;
        __syncthreads();
        unsigned int pk[10];
        int bk[10];
#pragma unroll
        for (int r = 0; r < 10; r++) {
            int e = e0 + r * 256 + tid;
            int s = __builtin_nontemporal_load(ei + e);
            int d = __builtin_nontemporal_load(ei + N_EDGES + e);
            int t = __builtin_nontemporal_load(et + e);
            pk[r] = (unsigned int)s | ((unsigned int)t << 15) | ((unsigned int)d << 17);
            bk[r] = d >> 7;
            atomicAdd(&hist[bk[r]], 1);
        }
        __syncthreads();
        int v = (tid < NBUCK) ? hist[tid] : 0;
        sbuf[tid] = v;
        __syncthreads();
        for (int o = 1; o < 256; o <<= 1) {
            int t = (tid >= o) ? sbuf[tid - o] : 0;
            __syncthreads();
            sbuf[tid] += t;
            __syncthreads();
        }
        if (tid < NBUCK) { start[tid] = sbuf[tid] - v; cur[tid] = sbuf[tid] - v; }
        __syncthreads();
#pragma unroll
        for (int r = 0; r < 10; r++) {
            int p = atomicAdd(&cur[bk[r]], 1);
            ord[p] = pk[r];
        }
        __syncthreads();
        for (int bb = tid; bb < NBUCK; bb += 256)
            if (hist[bb] > 0) gbase[bb] = atomicAdd(bucket_cursor + bb, hist[bb]);
        __syncthreads();
        for (int p = tid; p < CHUNK; p += 256) {
            unsigned int e = ord[p];
            int bb = (int)(e >> 24);
            int gp = gbase[bb] + (p - start[bb]);
            if (gp < BCAP)
                __builtin_nontemporal_store(e, breg + (size_t)bb * BCAP + gp);
        }
    } else if (b < 1500) {               // convx: bf16 copy + fp8 shadow
        int bf = local_flag((const unsigned short*)Ws1, (int*)smem);
        int idx = (b - 250) * 256 + tid;  // 8-elem chunk
        float f[8];
        if (bf) {
            uint4 v = reinterpret_cast<const uint4*>(x)[idx];
            reinterpret_cast<uint4*>(xc)[idx] = v;
            f[0] = bflo(v.x); f[1] = bfhi(v.x);
            f[2] = bflo(v.y); f[3] = bfhi(v.y);
            f[4] = bflo(v.z); f[5] = bfhi(v.z);
            f[6] = bflo(v.w); f[7] = bfhi(v.w);
        } else {
            const float* xf = reinterpret_cast<const float*>(x) + (size_t)idx * 8;
            unsigned short r[8] __attribute__((aligned(16)));
#pragma unroll
            for (int j = 0; j < 8; j++) { f[j] = xf[j]; r[j] = f2bf(xf[j]); }
            reinterpret_cast<uint4*>(xc)[idx] = *reinterpret_cast<const uint4*>(r);
        }
        int lo = 0, hi = 0;
        lo = __builtin_amdgcn_cvt_pk_fp8_f32(f[0], f[1], lo, false);
        lo = __builtin_amdgcn_cvt_pk_fp8_f32(f[2], f[3], lo, true);
        hi = __builtin_amdgcn_cvt_pk_fp8_f32(f[4], f[5], hi, false);
        hi = __builtin_amdgcn_cvt_pk_fp8_f32(f[6], f[7], hi, true);
        xc8[idx * 2]     = (unsigned int)lo;
        xc8[idx * 2 + 1] = (unsigned int)hi;
    } else if (b < 2140) {               // packW1
        int bf = local_flag((const unsigned short*)Ws1, (int*)smem);
        int idx = (b - 1500) * 256 + tid;
        int n = idx / 640, k = idx - n * 640;
        const void* p = (k < 128) ? Ws1 : Wt1;
        size_t src = (k < 128) ? ((size_t)k * 256 + n) : ((size_t)(k - 128) * 256 + n);
        WT1[idx] = bf ? ((const unsigned short*)p)[src] : f2bf(((const float*)p)[src]);
    } else if (b < 3420) {               // packW2
        int bf = local_flag((const unsigned short*)Ws1, (int*)smem);
        int idx = (b - 2140) * 256 + tid;
        int n = idx / 1280, k = idx - n * 1280;
        const void* p = (k < 256) ? Ws2 : Wt2;
        size_t src = (k < 256) ? ((size_t)k * 256 + n) : ((size_t)(k - 256) * 256 + n);
        WT2[idx] = bf ? ((const unsigned short*)p)[src] : f2bf(((const float*)p)[src]);
    } else {
        int bf = local_flag((const unsigned short*)Ws1, (int*)smem);
        if (tid == 0) *flag = bf;
    }
}

// Pass B: per-bucket counting sort -> perm + offsets4 (parallel scans).
__global__ __launch_bounds__(256) void bucketB_kernel(
        const unsigned int* __restrict__ breg,
        const int* __restrict__ bucket_cursor,
        unsigned short* __restrict__ perm,
        int* __restrict__ offsets4) {
    __shared__ int cnt[512], off[512];
    __shared__ int buf[256], pscan[256];
    int b = blockIdx.x, tid = threadIdx.x;
    int cv = (tid < NBUCK) ? bucket_cursor[tid] : 0;
    if (cv > BCAP) cv = BCAP;
    buf[tid] = cv;
    __syncthreads();
    for (int o = 1; o < 256; o <<= 1) {
        int t = (tid >= o) ? buf[tid - o] : 0;
        __syncthreads();
        buf[tid] += t;
        __syncthreads();
    }
    int obase = (b > 0) ? buf[b - 1] : 0;
    if (b == 0 && tid == 0) offsets4[NT4] = buf[255];
    int Eb = bucket_cursor[b];
    if (Eb > BCAP) Eb = BCAP;
    for (int i = tid; i < 512; i += 256) cnt[i] = 0;
    __syncthreads();
    const unsigned int* reg = breg + (size_t)b * BCAP;
    for (int i = tid; i < Eb; i += 256) {
        unsigned int e = reg[i];
        int seg = (((e >> 17) & 127) << 2) | ((e >> 15) & 3);
        atomicAdd(&cnt[seg], 1);
    }
    __syncthreads();
    int pv = cnt[2 * tid] + cnt[2 * tid + 1];
    pscan[tid] = pv;
    __syncthreads();
    for (int o = 1; o < 256; o <<= 1) {
        int t = (tid >= o) ? pscan[tid - o] : 0;
        __syncthreads();
        pscan[tid] += t;
        __syncthreads();
    }
    int pexcl = pscan[tid] - pv;
    off[2 * tid]     = pexcl;
    off[2 * tid + 1] = pexcl + cnt[2 * tid];
    __syncthreads();
    for (int i = tid; i < 512; i += 256) {
        int node = b * 128 + (i >> 2);
        if (node < N_NODES) offsets4[node * 4 + (i & 3)] = obase + off[i];
    }
    __syncthreads();
    for (int i = tid; i < Eb; i += 256) {
        unsigned int e = reg[i];
        int seg = (((e >> 17) & 127) << 2) | ((e >> 15) & 3);
        int p = atomicAdd(&off[seg], 1);
        perm[obase + p] = (unsigned short)(e & 0x7fff);
    }
}

// ---------- typed aggregation: fp8 gather, f32 accumulate ------------------
// Subgroup of G = D/8 lanes, each loading uint2 (8 fp8); NSUB = 64/G
// subgroups gather independent edges, ILP4. Wave-uniform tail (R10 fix).
template <int D>
__global__ __launch_bounds__(256) void agg8_kernel(
        const unsigned int* __restrict__ F8,     // [N, D] fp8 (uint-chunked)
        const int* __restrict__ offs4,
        const unsigned short* __restrict__ perm,
        unsigned short* __restrict__ AG) {       // [N, 4*D] bf16
    constexpr int G = D / 8;                     // 16 (D=128) or 32 (D=256)
    constexpr int NSUB = 64 / G;                 // 4 or 2
    int wave = threadIdx.x >> 6, lane = threadIdx.x & 63;
    int sg = lane / G;
    int gl = lane - sg * G;
    for (int n = blockIdx.x * 4 + wave; n < N_NODES; n += gridDim.x * 4) {
        int o0 = offs4[n * 4];
        int o4 = offs4[n * 4 + 4];
        int deg = o4 - o0;
        float inv = 1.0f / (float)(deg > 1 ? deg : 1);
        int s0 = o0;
#pragma unroll
        for (int t = 0; t < 4; t++) {
            int s1 = offs4[n * 4 + t + 1];
            float a[8];
#pragma unroll
            for (int v = 0; v < 8; v++) a[v] = 0.f;
            int j = s0;
            while (j < s1) {
                int m = s1 - j;
                if (m > 64) m = 64;
                int pw = (int)perm[j + ((lane < m) ? lane : 0)];
                int nfull = (m / (NSUB * 4)) * (NSUB * 4);
                for (int base = 0; base < nfull; base += NSUB * 4) {
                    uint2 x[4];
#pragma unroll
                    for (int l = 0; l < 4; l++) {
                        int src = __shfl(pw, base + sg * 4 + l);
                        x[l] = *reinterpret_cast<const uint2*>(F8 + (size_t)src * (D / 4) + gl * 2);
                    }
#pragma unroll
                    for (int l = 0; l < 4; l++) {
                        v2f p0 = __builtin_amdgcn_cvt_pk_f32_fp8((int)x[l].x, false);
                        v2f p1 = __builtin_amdgcn_cvt_pk_f32_fp8((int)x[l].x, true);
                        v2f p2 = __builtin_amdgcn_cvt_pk_f32_fp8((int)x[l].y, false);
                        v2f p3 = __builtin_amdgcn_cvt_pk_f32_fp8((int)x[l].y, true);
                        a[0] += p0.x; a[1] += p0.y;
                        a[2] += p1.x; a[3] += p1.y;
                        a[4] += p2.x; a[5] += p2.y;
                        a[6] += p3.x; a[7] += p3.y;
                    }
                }
                for (int k = nfull; k < m; k += NSUB) {
                    int e = k + sg;
                    int valid = (e < m);
                    int idx = valid ? e : (m - 1);
                    int src = __shfl(pw, idx);
                    uint2 x = *reinterpret_cast<const uint2*>(F8 + (size_t)src * (D / 4) + gl * 2);
                    unsigned msk = valid ? 0xffffffffu : 0u;  // fp8 0x00 == +0.0
                    x.x &= msk; x.y &= msk;
                    v2f p0 = __builtin_amdgcn_cvt_pk_f32_fp8((int)x.x, false);
                    v2f p1 = __builtin_amdgcn_cvt_pk_f32_fp8((int)x.x, true);
                    v2f p2 = __builtin_amdgcn_cvt_pk_f32_fp8((int)x.y, false);
                    v2f p3 = __builtin_amdgcn_cvt_pk_f32_fp8((int)x.y, true);
                    a[0] += p0.x; a[1] += p0.y;
                    a[2] += p1.x; a[3] += p1.y;
                    a[4] += p2.x; a[5] += p2.y;
                    a[6] += p3.x; a[7] += p3.y;
                }
                j += m;
            }
#pragma unroll
            for (int v = 0; v < 8; v++) {
                float s = a[v];
                s += __shfl_xor(s, G);
                if (NSUB == 4) s += __shfl_xor(s, 2 * G);
                a[v] = s * inv;
            }
            if (sg == 0) {
                unsigned short r[8] __attribute__((aligned(16)));
#pragma unroll
                for (int v = 0; v < 8; v++) r[v] = f2bf(a[v]);
                *reinterpret_cast<uint4*>(AG + (size_t)n * (4 * D) + t * D + gl * 8) =
                    *reinterpret_cast<const uint4*>(r);
            }
            s0 = s1;
        }
    }
}

// ---------- MFMA GEMM: C[M,256] = [X | AG] @ WT^T + bias -------------------
// R16: 2-phase double-buffered schedule (catalog T3-minimum).
// 128x128 tile, BK=64, 4 waves, gload16 staging into LINEAR LDS.
// Per K-step: issue STAGE(t+1) into buf^1 FIRST, then ds_read+MFMA on
// buf, then ONE __syncthreads (emits vmcnt(0) drain) — staging latency
// hides under the compute phase. R15's serial stage->sync->compute was
// latency-bound at 1.2 blocks/CU (MfmaUtil 8.8%).
template <int D>
__global__ __launch_bounds__(256) void gemm_kernel(
        const unsigned short* __restrict__ X,
        const unsigned short* __restrict__ AG,
        const unsigned short* __restrict__ BT,
        const void* __restrict__ bias,
        const int* __restrict__ flagp,
        unsigned short* __restrict__ C,
        unsigned char* __restrict__ C8,          // fp8 shadow (or nullptr)
        int M, int relu) {
    constexpr int K = 5 * D;
    constexpr int NSTEP = K / 64;
    __shared__ __align__(16) unsigned short As[2 * 128 * 64];
    __shared__ __align__(16) unsigned short Bs[2 * 128 * 64];
    int b = blockIdx.x;
    int mt = (b >> 4) * 8 + (b & 7);   // [0,160)
    int nt = (b >> 3) & 1;
    int mtiles = (M + 127) >> 7;
    if (mt >= mtiles) return;
    int m0 = mt * 128;
    int n0 = nt * 128;
    int tid  = threadIdx.x;
    int wave = tid >> 6, lane = tid & 63;
    int wm = wave >> 1, wn = wave & 1;        // each wave: 64x64 output
    int quad = lane >> 4, l16 = lane & 15;

    f32x4 acc[4][4];
#pragma unroll
    for (int i = 0; i < 4; i++)
#pragma unroll
        for (int j = 0; j < 4; j++) acc[i][j] = (f32x4){0.f, 0.f, 0.f, 0.f};

    // staging addresses are affine in t; precompute per-thread row/col
    int srow = tid >> 3;          // 0..31 (row block; +32 per p)
    int sc8  = tid & 7;

    auto stage = [&](int t, int buf) {
        int k0 = t * 64;
        const unsigned short* abase = (k0 < D) ? X : AG;
        int rs  = (k0 < D) ? D : 4 * D;
        int col = (k0 < D) ? k0 : (k0 - D);
        unsigned short* As_ = As + buf * (128 * 64);
        unsigned short* Bs_ = Bs + buf * (128 * 64);
#pragma unroll
        for (int p = 0; p < 4; p++) {
            int c   = p * 256 + tid;
            int row = srow + p * 32;
            int gr  = m0 + row;
            if (gr >= M) gr = M - 1;          // clamp: only rows >= M affected
            gload16(abase + (size_t)gr * rs + col + sc8 * 8, As_ + c * 8);
        }
#pragma unroll
        for (int p = 0; p < 4; p++) {
            int c   = p * 256 + tid;
            int row = srow + p * 32;
            gload16(BT + (size_t)(n0 + row) * K + k0 + sc8 * 8, Bs_ + c * 8);
        }
    };

    stage(0, 0);
    __syncthreads();                 // drain prologue stage
    int cur = 0;
    for (int t = 0; t < NSTEP; t++) {
        if (t + 1 < NSTEP) stage(t + 1, cur ^ 1);
        const unsigned short* As_ = As + cur * (128 * 64);
        const unsigned short* Bs_ = Bs + cur * (128 * 64);
#pragma unroll
        for (int ks = 0; ks < 2; ks++) {
            v8bf af[4], bfr[4];
#pragma unroll
            for (int i = 0; i < 4; i++)
                af[i] = *reinterpret_cast<const v8bf*>(
                    &As_[(wm * 64 + i * 16 + l16) * 64 + ks * 32 + quad * 8]);
#pragma unroll
            for (int j = 0; j < 4; j++)
                bfr[j] = *reinterpret_cast<const v8bf*>(
                    &Bs_[(wn * 64 + j * 16 + l16) * 64 + ks * 32 + quad * 8]);
#pragma unroll
            for (int i = 0; i < 4; i++)
#pragma unroll
                for (int j = 0; j < 4; j++)
                    acc[i][j] = __builtin_amdgcn_mfma_f32_16x16x32_bf16(af[i], bfr[j], acc[i][j], 0, 0, 0);
        }
        __syncthreads();             // vmcnt(0)+lgkmcnt(0) drain + barrier
        cur ^= 1;
    }
    int bf = *flagp;
#pragma unroll
    for (int i = 0; i < 4; i++) {
#pragma unroll
        for (int j = 0; j < 4; j++) {
            int col = n0 + wn * 64 + j * 16 + l16;
            float bv = bf ? bf2f(((const unsigned short*)bias)[col])
                          : ((const float*)bias)[col];
#pragma unroll
            for (int r = 0; r < 4; r++) {
                int row = m0 + wm * 64 + i * 16 + quad * 4 + r;
                if (row < M) {
                    float v = acc[i][j][r] + bv;
                    if (relu) v = fmaxf(v, 0.0f);
                    C[(size_t)row * 256 + col] = f2bf(v);
                    if (C8) {
                        int pk = __builtin_amdgcn_cvt_pk_fp8_f32(v, v, 0, false);
                        C8[(size_t)row * 256 + col] = (unsigned char)(pk & 0xff);
                    }
                }
            }
        }
    }
}

// ---------- classifier head ------------------------------------------------
__global__ void cls_kernel(const unsigned short* __restrict__ h2,
                           const int* __restrict__ aidx,
                           const void* __restrict__ Wc,
                           const void* __restrict__ bc,
                           const int* __restrict__ flagp,
                           void* __restrict__ out) {
    int lin = blockIdx.x * blockDim.x + threadIdx.x;
    int a = lin >> 6, lane = lin & 63;
    if (a >= N_ASPECTS) return;
    int bf = *flagp;
    int node = aidx[a];
    uint2 v = *reinterpret_cast<const uint2*>(h2 + (size_t)node * 256 + lane * 4);
    float hv[4] = {bflo(v.x), bfhi(v.x), bflo(v.y), bfhi(v.y)};
    float a0 = 0.f, a1 = 0.f, a2 = 0.f;
#pragma unroll
    for (int r = 0; r < 4; r++) {
        int k = lane * 4 + r;
        float w0 = bf ? bf2f(((const unsigned short*)Wc)[k * 3 + 0]) : ((const float*)Wc)[k * 3 + 0];
        float w1 = bf ? bf2f(((const unsigned short*)Wc)[k * 3 + 1]) : ((const float*)Wc)[k * 3 + 1];
        float w2 = bf ? bf2f(((const unsigned short*)Wc)[k * 3 + 2]) : ((const float*)Wc)[k * 3 + 2];
        a0 += hv[r] * w0;
        a1 += hv[r] * w1;
        a2 += hv[r] * w2;
    }
#pragma unroll
    for (int off = 32; off >= 1; off >>= 1) {
        a0 += __shfl_down(a0, off);
        a1 += __shfl_down(a1, off);
        a2 += __shfl_down(a2, off);
    }
    if (lane == 0) {
        float b0 = bf ? bf2f(((const unsigned short*)bc)[0]) : ((const float*)bc)[0];
        float b1 = bf ? bf2f(((const unsigned short*)bc)[1]) : ((const float*)bc)[1];
        float b2 = bf ? bf2f(((const unsigned short*)bc)[2]) : ((const float*)bc)[2];
        if (bf) {
            unsigned short* o = (unsigned short*)out;
            o[a * 3 + 0] = f2bf(a0 + b0);
            o[a * 3 + 1] = f2bf(a1 + b1);
            o[a * 3 + 2] = f2bf(a2 + b2);
        } else {
            float* o = (float*)out;
            o[a * 3 + 0] = a0 + b0;
            o[a * 3 + 1] = a1 + b1;
            o[a * 3 + 2] = a2 + b2;
        }
    }
}

extern "C" void kernel_launch(void* const* d_in, const int* in_sizes, int n_in,
                              void* d_out, int out_size, void* d_ws, size_t ws_size,
                              hipStream_t stream) {
    const void* x   = d_in[0];
    const void* Wt1 = d_in[1];
    const void* Ws1 = d_in[2];
    const void* b1  = d_in[3];
    const void* Wt2 = d_in[4];
    const void* Ws2 = d_in[5];
    const void* b2  = d_in[6];
    const void* Wc  = d_in[7];
    const void* bc  = d_in[8];
    const int* ei = (const int*)d_in[9];
    const int* et = (const int*)d_in[10];
    const int* ai = (const int*)d_in[11];

    char* ws = (char*)d_ws;
    size_t off = 0;
    auto alloc = [&](size_t bytes) {
        void* p = ws + off;
        off += (bytes + 255) & ~(size_t)255;
        return p;
    };
    int*            flag          = (int*)alloc(4);
    int*            bucket_cursor = (int*)alloc((size_t)NBUCK * 4);
    int*            offsets4      = (int*)alloc((size_t)(NT4 + 1) * 4);
    unsigned int*   breg          = (unsigned int*)alloc((size_t)NBUCK * BCAP * 4); // 3.2 MB
    unsigned short* perm          = (unsigned short*)alloc((size_t)N_EDGES * 2);
    unsigned short* xc            = (unsigned short*)alloc((size_t)N_NODES * IN_DIM * 2);
    unsigned int*   xc8           = (unsigned int*)alloc((size_t)N_NODES * IN_DIM);    // 2.6 MB fp8
    unsigned short* AG            = (unsigned short*)alloc((size_t)N_NODES * 4 * HID_DIM * 2);
    unsigned short* h             = (unsigned short*)alloc((size_t)N_NODES * HID_DIM * 2);
    unsigned char*  h8            = (unsigned char*)alloc((size_t)N_NODES * HID_DIM);  // 5.1 MB fp8
    unsigned short* h2            = (unsigned short*)alloc((size_t)N_NODES * HID_DIM * 2);
    unsigned short* WT1           = (unsigned short*)alloc((size_t)640 * 256 * 2);
    unsigned short* WT2           = (unsigned short*)alloc((size_t)1280 * 256 * 2);
    // total ~60 MB

    hipMemsetAsync(bucket_cursor, 0, (size_t)NBUCK * 4, stream);
    prepA_kernel<<<3421, 256, 0, stream>>>(x, Ws1, Wt1, Ws2, Wt2, ei, et,
                                           xc, xc8, WT1, WT2, bucket_cursor, breg, flag);
    bucketB_kernel<<<NBUCK, 256, 0, stream>>>(breg, bucket_cursor, perm, offsets4);

    // Layer 1 (fp8 gather on x; self-term X stays bf16)
    agg8_kernel<IN_DIM><<<4096, 256, 0, stream>>>(xc8, offsets4, perm, AG);
    gemm_kernel<IN_DIM><<<320, 256, 0, stream>>>(xc, AG, WT1, b1, flag, h, h8, N_NODES, 1);
    // Layer 2 (fp8 shadow emitted by gemm1's epilogue)
    agg8_kernel<HID_DIM><<<4096, 256, 0, stream>>>((const unsigned int*)h8, offsets4, perm, AG);
    gemm_kernel<HID_DIM><<<320, 256, 0, stream>>>(h, AG, WT2, b2, flag, h2, nullptr, N_NODES, 0);
    // Head
    cls_kernel<<<(N_ASPECTS * 64) / 256, 256, 0, stream>>>(h2, ai, Wc, bc, flag, d_out);
}

// Round 3
// 239.492 us; speedup vs baseline: 1.0206x; 1.0077x over previous
//
#include <hip/hip_runtime.h>

#define N_NODES   20000
#define N_EDGES   640000
#define IN_DIM    128
#define HID_DIM   256
#define N_TYPES   4
#define N_ASPECTS 4096
#define NT4       (N_NODES * N_TYPES)   // 80000 CSR segments
#define NBUCK     157                   // dst buckets of 128 nodes
#define BCAP      5120                  // bucket capacity (mean 4096 + 16 sigma)
#define CHUNK     2560                  // edges per bucketA block (250 blocks exact)

typedef __bf16 v8bf __attribute__((ext_vector_type(8)));
typedef float  f32x4 __attribute__((ext_vector_type(4)));
typedef float  v2f   __attribute__((ext_vector_type(2)));

static __device__ __forceinline__ float bf2f(unsigned short u) {
    return __builtin_bit_cast(float, ((unsigned int)u) << 16);
}
static __device__ __forceinline__ float bflo(unsigned int u) {
    return __builtin_bit_cast(float, u << 16);
}
static __device__ __forceinline__ float bfhi(unsigned int u) {
    return __builtin_bit_cast(float, u & 0xffff0000u);
}
// f32 -> bf16 round-to-nearest-even (finite values)
static __device__ __forceinline__ unsigned short f2bf(float f) {
    unsigned int u = __builtin_bit_cast(unsigned int, f);
    u += 0x7fffu + ((u >> 16) & 1u);
    return (unsigned short)(u >> 16);
}

// async global->LDS, 16B per lane (m97 pattern: LDS dest linear in lane)
static __device__ __forceinline__ void gload16(const unsigned short* g, unsigned short* l) {
    __builtin_amdgcn_global_load_lds(
        (const __attribute__((address_space(1))) void*)g,
        (__attribute__((address_space(3))) void*)l,
        16, 0, 0);
}

// counted vector-memory wait (T4): leaves N loads in flight
#define VMWAIT(N) asm volatile("s_waitcnt vmcnt(" #N ")" ::: "memory")

// Per-block dtype detection: 1 KB sample of W_self1.
static __device__ __forceinline__ int local_flag(const unsigned short* w, int* red) {
    int tid = threadIdx.x;
    int c = 0;
    for (int i = tid; i < 1024; i += 256) {
        unsigned hb = (w[i] >> 8) & 0x7f;
        c += (hb >= 0x39 && hb <= 0x3D) ? 1 : 0;
    }
#pragma unroll
    for (int off = 32; off >= 1; off >>= 1) c += __shfl_down(c, off);
    if ((tid & 63) == 0) red[tid >> 6] = c;
    __syncthreads();
    int tot = red[0] + red[1] + red[2] + red[3];
    __syncthreads();
    return (tot >= 768) ? 1 : 0;
}

// ---------- fused: bucketA | convx(+fp8) | packW1 | packW2 | flag ----------
__global__ __launch_bounds__(256) void prepA_kernel(
        const void* __restrict__ x,
        const void* __restrict__ Ws1, const void* __restrict__ Wt1,
        const void* __restrict__ Ws2, const void* __restrict__ Wt2,
        const int* __restrict__ ei, const int* __restrict__ et,
        unsigned short* __restrict__ xc,
        unsigned int* __restrict__ xc8,
        unsigned short* __restrict__ WT1,
        unsigned short* __restrict__ WT2,
        int* __restrict__ bucket_cursor,
        unsigned int* __restrict__ breg,
        int* __restrict__ flag) {
    __shared__ __align__(16) char smem[14336];
    int b = blockIdx.x, tid = threadIdx.x;
    if (b < 250) {
        unsigned int* ord = (unsigned int*)smem;             // 2560*4 = 10240
        int* hist  = (int*)(smem + 10240);
        int* start = hist + NBUCK;
        int* cur   = start + NBUCK;
        int* gbase = cur + NBUCK;
        int* sbuf  = gbase + NBUCK;
        int e0 = b * CHUNK;
        for (int i = tid; i < NBUCK; i += 256) hist[i] = 0;
        __syncthreads();
        unsigned int pk[10];
        int bk[10];
#pragma unroll
        for (int r = 0; r < 10; r++) {
            int e = e0 + r * 256 + tid;
            int s = __builtin_nontemporal_load(ei + e);
            int d = __builtin_nontemporal_load(ei + N_EDGES + e);
            int t = __builtin_nontemporal_load(et + e);
            pk[r] = (unsigned int)s | ((unsigned int)t << 15) | ((unsigned int)d << 17);
            bk[r] = d >> 7;
            atomicAdd(&hist[bk[r]], 1);
        }
        __syncthreads();
        int v = (tid < NBUCK) ? hist[tid] : 0;
        sbuf[tid] = v;
        __syncthreads();
        for (int o = 1; o < 256; o <<= 1) {
            int t = (tid >= o) ? sbuf[tid - o] : 0;
            __syncthreads();
            sbuf[tid] += t;
            __syncthreads();
        }
        if (tid < NBUCK) { start[tid] = sbuf[tid] - v; cur[tid] = sbuf[tid] - v; }
        __syncthreads();
#pragma unroll
        for (int r = 0; r < 10; r++) {
            int p = atomicAdd(&cur[bk[r]], 1);
            ord[p] = pk[r];
        }
        __syncthreads();
        for (int bb = tid; bb < NBUCK; bb += 256)
            if (hist[bb] > 0) gbase[bb] = atomicAdd(bucket_cursor + bb, hist[bb]);
        __syncthreads();
        for (int p = tid; p < CHUNK; p += 256) {
            unsigned int e = ord[p];
            int bb = (int)(e >> 24);
            int gp = gbase[bb] + (p - start[bb]);
            if (gp < BCAP)
                __builtin_nontemporal_store(e, breg + (size_t)bb * BCAP + gp);
        }
    } else if (b < 1500) {               // convx: bf16 copy + fp8 shadow
        int bf = local_flag((const unsigned short*)Ws1, (int*)smem);
        int idx = (b - 250) * 256 + tid;  // 8-elem chunk
        float f[8];
        if (bf) {
            uint4 v = reinterpret_cast<const uint4*>(x)[idx];
            reinterpret_cast<uint4*>(xc)[idx] = v;
            f[0] = bflo(v.x); f[1] = bfhi(v.x);
            f[2] = bflo(v.y); f[3] = bfhi(v.y);
            f[4] = bflo(v.z); f[5] = bfhi(v.z);
            f[6] = bflo(v.w); f[7] = bfhi(v.w);
        } else {
            const float* xf = reinterpret_cast<const float*>(x) + (size_t)idx * 8;
            unsigned short r[8] __attribute__((aligned(16)));
#pragma unroll
            for (int j = 0; j < 8; j++) { f[j] = xf[j]; r[j] = f2bf(xf[j]); }
            reinterpret_cast<uint4*>(xc)[idx] = *reinterpret_cast<const uint4*>(r);
        }
        int lo = 0, hi = 0;
        lo = __builtin_amdgcn_cvt_pk_fp8_f32(f[0], f[1], lo, false);
        lo = __builtin_amdgcn_cvt_pk_fp8_f32(f[2], f[3], lo, true);
        hi = __builtin_amdgcn_cvt_pk_fp8_f32(f[4], f[5], hi, false);
        hi = __builtin_amdgcn_cvt_pk_fp8_f32(f[6], f[7], hi, true);
        xc8[idx * 2]     = (unsigned int)lo;
        xc8[idx * 2 + 1] = (unsigned int)hi;
    } else if (b < 2140) {               // packW1
        int bf = local_flag((const unsigned short*)Ws1, (int*)smem);
        int idx = (b - 1500) * 256 + tid;
        int n = idx / 640, k = idx - n * 640;
        const void* p = (k < 128) ? Ws1 : Wt1;
        size_t src = (k < 128) ? ((size_t)k * 256 + n) : ((size_t)(k - 128) * 256 + n);
        WT1[idx] = bf ? ((const unsigned short*)p)[src] : f2bf(((const float*)p)[src]);
    } else if (b < 3420) {               // packW2
        int bf = local_flag((const unsigned short*)Ws1, (int*)smem);
        int idx = (b - 2140) * 256 + tid;
        int n = idx / 1280, k = idx - n * 1280;
        const void* p = (k < 256) ? Ws2 : Wt2;
        size_t src = (k < 256) ? ((size_t)k * 256 + n) : ((size_t)(k - 256) * 256 + n);
        WT2[idx] = bf ? ((const unsigned short*)p)[src] : f2bf(((const float*)p)[src]);
    } else {
        int bf = local_flag((const unsigned short*)Ws1, (int*)smem);
        if (tid == 0) *flag = bf;
    }
}

// Pass B: per-bucket counting sort -> perm + offsets4 (parallel scans).
__global__ __launch_bounds__(256) void bucketB_kernel(
        const unsigned int* __restrict__ breg,
        const int* __restrict__ bucket_cursor,
        unsigned short* __restrict__ perm,
        int* __restrict__ offsets4) {
    __shared__ int cnt[512], off[512];
    __shared__ int buf[256], pscan[256];
    int b = blockIdx.x, tid = threadIdx.x;
    int cv = (tid < NBUCK) ? bucket_cursor[tid] : 0;
    if (cv > BCAP) cv = BCAP;
    buf[tid] = cv;
    __syncthreads();
    for (int o = 1; o < 256; o <<= 1) {
        int t = (tid >= o) ? buf[tid - o] : 0;
        __syncthreads();
        buf[tid] += t;
        __syncthreads();
    }
    int obase = (b > 0) ? buf[b - 1] : 0;
    if (b == 0 && tid == 0) offsets4[NT4] = buf[255];
    int Eb = bucket_cursor[b];
    if (Eb > BCAP) Eb = BCAP;
    for (int i = tid; i < 512; i += 256) cnt[i] = 0;
    __syncthreads();
    const unsigned int* reg = breg + (size_t)b * BCAP;
    for (int i = tid; i < Eb; i += 256) {
        unsigned int e = reg[i];
        int seg = (((e >> 17) & 127) << 2) | ((e >> 15) & 3);
        atomicAdd(&cnt[seg], 1);
    }
    __syncthreads();
    int pv = cnt[2 * tid] + cnt[2 * tid + 1];
    pscan[tid] = pv;
    __syncthreads();
    for (int o = 1; o < 256; o <<= 1) {
        int t = (tid >= o) ? pscan[tid - o] : 0;
        __syncthreads();
        pscan[tid] += t;
        __syncthreads();
    }
    int pexcl = pscan[tid] - pv;
    off[2 * tid]     = pexcl;
    off[2 * tid + 1] = pexcl + cnt[2 * tid];
    __syncthreads();
    for (int i = tid; i < 512; i += 256) {
        int node = b * 128 + (i >> 2);
        if (node < N_NODES) offsets4[node * 4 + (i & 3)] = obase + off[i];
    }
    __syncthreads();
    for (int i = tid; i < Eb; i += 256) {
        unsigned int e = reg[i];
        int seg = (((e >> 17) & 127) << 2) | ((e >> 15) & 3);
        int p = atomicAdd(&off[seg], 1);
        perm[obase + p] = (unsigned short)(e & 0x7fff);
    }
}

// ---------- typed aggregation: fp8 gather, f32 accumulate ------------------
// Subgroup of G = D/8 lanes, each loading uint2 (8 fp8); NSUB = 64/G
// subgroups gather independent edges, ILP4. Wave-uniform tail (R10 fix).
template <int D>
__global__ __launch_bounds__(256) void agg8_kernel(
        const unsigned int* __restrict__ F8,     // [N, D] fp8 (uint-chunked)
        const int* __restrict__ offs4,
        const unsigned short* __restrict__ perm,
        unsigned short* __restrict__ AG) {       // [N, 4*D] bf16
    constexpr int G = D / 8;                     // 16 (D=128) or 32 (D=256)
    constexpr int NSUB = 64 / G;                 // 4 or 2
    int wave = threadIdx.x >> 6, lane = threadIdx.x & 63;
    int sg = lane / G;
    int gl = lane - sg * G;
    for (int n = blockIdx.x * 4 + wave; n < N_NODES; n += gridDim.x * 4) {
        int o0 = offs4[n * 4];
        int o4 = offs4[n * 4 + 4];
        int deg = o4 - o0;
        float inv = 1.0f / (float)(deg > 1 ? deg : 1);
        int s0 = o0;
#pragma unroll
        for (int t = 0; t < 4; t++) {
            int s1 = offs4[n * 4 + t + 1];
            float a[8];
#pragma unroll
            for (int v = 0; v < 8; v++) a[v] = 0.f;
            int j = s0;
            while (j < s1) {
                int m = s1 - j;
                if (m > 64) m = 64;
                int pw = (int)perm[j + ((lane < m) ? lane : 0)];
                int nfull = (m / (NSUB * 4)) * (NSUB * 4);
                for (int base = 0; base < nfull; base += NSUB * 4) {
                    uint2 x[4];
#pragma unroll
                    for (int l = 0; l < 4; l++) {
                        int src = __shfl(pw, base + sg * 4 + l);
                        x[l] = *reinterpret_cast<const uint2*>(F8 + (size_t)src * (D / 4) + gl * 2);
                    }
#pragma unroll
                    for (int l = 0; l < 4; l++) {
                        v2f p0 = __builtin_amdgcn_cvt_pk_f32_fp8((int)x[l].x, false);
                        v2f p1 = __builtin_amdgcn_cvt_pk_f32_fp8((int)x[l].x, true);
                        v2f p2 = __builtin_amdgcn_cvt_pk_f32_fp8((int)x[l].y, false);
                        v2f p3 = __builtin_amdgcn_cvt_pk_f32_fp8((int)x[l].y, true);
                        a[0] += p0.x; a[1] += p0.y;
                        a[2] += p1.x; a[3] += p1.y;
                        a[4] += p2.x; a[5] += p2.y;
                        a[6] += p3.x; a[7] += p3.y;
                    }
                }
                for (int k = nfull; k < m; k += NSUB) {
                    int e = k + sg;
                    int valid = (e < m);
                    int idx = valid ? e : (m - 1);
                    int src = __shfl(pw, idx);
                    uint2 x = *reinterpret_cast<const uint2*>(F8 + (size_t)src * (D / 4) + gl * 2);
                    unsigned msk = valid ? 0xffffffffu : 0u;  // fp8 0x00 == +0.0
                    x.x &= msk; x.y &= msk;
                    v2f p0 = __builtin_amdgcn_cvt_pk_f32_fp8((int)x.x, false);
                    v2f p1 = __builtin_amdgcn_cvt_pk_f32_fp8((int)x.x, true);
                    v2f p2 = __builtin_amdgcn_cvt_pk_f32_fp8((int)x.y, false);
                    v2f p3 = __builtin_amdgcn_cvt_pk_f32_fp8((int)x.y, true);
                    a[0] += p0.x; a[1] += p0.y;
                    a[2] += p1.x; a[3] += p1.y;
                    a[4] += p2.x; a[5] += p2.y;
                    a[6] += p3.x; a[7] += p3.y;
                }
                j += m;
            }
#pragma unroll
            for (int v = 0; v < 8; v++) {
                float s = a[v];
                s += __shfl_xor(s, G);
                if (NSUB == 4) s += __shfl_xor(s, 2 * G);
                a[v] = s * inv;
            }
            if (sg == 0) {
                unsigned short r[8] __attribute__((aligned(16)));
#pragma unroll
                for (int v = 0; v < 8; v++) r[v] = f2bf(a[v]);
                *reinterpret_cast<uint4*>(AG + (size_t)n * (4 * D) + t * D + gl * 8) =
                    *reinterpret_cast<const uint4*>(r);
            }
            s0 = s1;
        }
    }
}

// ---------- MFMA GEMM: C[M,256] = [X | AG] @ WT^T + bias -------------------
// R17: T4 counted-vmcnt pipeline. 128x128 tile, BK=64, 4 waves, gload16
// into LINEAR LDS, 2 buffers, 2-deep prefetch. Each stage = exactly 8
// global_load_lds per lane, so vmcnt(8) after issuing stage(t+2) waits
// precisely for stage(t+1) while leaving the fresh 8 in flight.
// R16's __syncthreads drained vmcnt(0) incl. fresh loads => serial-
// equivalent (measured flat). Raw s_barrier + per-wave counted wait
// (m201 phase-4/8 pattern): wait own 8 -> barrier => tile complete.
template <int D>
__global__ __launch_bounds__(256) void gemm_kernel(
        const unsigned short* __restrict__ X,
        const unsigned short* __restrict__ AG,
        const unsigned short* __restrict__ BT,
        const void* __restrict__ bias,
        const int* __restrict__ flagp,
        unsigned short* __restrict__ C,
        unsigned char* __restrict__ C8,          // fp8 shadow (or nullptr)
        int M, int relu) {
    constexpr int K = 5 * D;
    constexpr int NSTEP = K / 64;
    __shared__ __align__(16) unsigned short As[2 * 128 * 64];
    __shared__ __align__(16) unsigned short Bs[2 * 128 * 64];
    int b = blockIdx.x;
    int mt = (b >> 4) * 8 + (b & 7);   // [0,160)
    int nt = (b >> 3) & 1;
    int mtiles = (M + 127) >> 7;
    if (mt >= mtiles) return;
    int m0 = mt * 128;
    int n0 = nt * 128;
    int tid  = threadIdx.x;
    int wave = tid >> 6, lane = tid & 63;
    int wm = wave >> 1, wn = wave & 1;        // each wave: 64x64 output
    int quad = lane >> 4, l16 = lane & 15;

    f32x4 acc[4][4];
#pragma unroll
    for (int i = 0; i < 4; i++)
#pragma unroll
        for (int j = 0; j < 4; j++) acc[i][j] = (f32x4){0.f, 0.f, 0.f, 0.f};

    int srow = tid >> 3;          // 0..31 (row block; +32 per p)
    int sc8  = tid & 7;

    auto stage = [&](int t, int buf) {
        int k0 = t * 64;
        const unsigned short* abase = (k0 < D) ? X : AG;
        int rs  = (k0 < D) ? D : 4 * D;
        int col = (k0 < D) ? k0 : (k0 - D);
        unsigned short* As_ = As + buf * (128 * 64);
        unsigned short* Bs_ = Bs + buf * (128 * 64);
#pragma unroll
        for (int p = 0; p < 4; p++) {
            int c   = p * 256 + tid;
            int row = srow + p * 32;
            int gr  = m0 + row;
            if (gr >= M) gr = M - 1;          // clamp: only rows >= M affected
            gload16(abase + (size_t)gr * rs + col + sc8 * 8, As_ + c * 8);
        }
#pragma unroll
        for (int p = 0; p < 4; p++) {
            int c   = p * 256 + tid;
            int row = srow + p * 32;
            gload16(BT + (size_t)(n0 + row) * K + k0 + sc8 * 8, Bs_ + c * 8);
        }
    };

    // prologue: 2-deep prefetch
    stage(0, 0);
    stage(1, 1);
    VMWAIT(8);                                  // own stage(0) loads landed
    __builtin_amdgcn_s_barrier();               // all waves' stage(0) landed
    __builtin_amdgcn_sched_barrier(0);
    int cur = 0;
    for (int t = 0; t < NSTEP; t++) {
        const unsigned short* As_ = As + cur * (128 * 64);
        const unsigned short* Bs_ = Bs + cur * (128 * 64);
#pragma unroll
        for (int ks = 0; ks < 2; ks++) {
            v8bf af[4], bfr[4];
#pragma unroll
            for (int i = 0; i < 4; i++)
                af[i] = *reinterpret_cast<const v8bf*>(
                    &As_[(wm * 64 + i * 16 + l16) * 64 + ks * 32 + quad * 8]);
#pragma unroll
            for (int j = 0; j < 4; j++)
                bfr[j] = *reinterpret_cast<const v8bf*>(
                    &Bs_[(wn * 64 + j * 16 + l16) * 64 + ks * 32 + quad * 8]);
#pragma unroll
            for (int i = 0; i < 4; i++)
#pragma unroll
                for (int j = 0; j < 4; j++)
                    acc[i][j] = __builtin_amdgcn_mfma_f32_16x16x32_bf16(af[i], bfr[j], acc[i][j], 0, 0, 0);
        }
        __builtin_amdgcn_s_barrier();           // all waves done reading cur
        if (t + 2 < NSTEP) {
            stage(t + 2, cur);                  // overwrite cur (safe post-barrier)
            VMWAIT(8);                          // own stage(t+1) landed
        } else {
            VMWAIT(0);                          // tail: drain remaining
        }
        __builtin_amdgcn_s_barrier();           // all waves' stage(t+1) landed
        __builtin_amdgcn_sched_barrier(0);
        cur ^= 1;
    }
    int bf = *flagp;
#pragma unroll
    for (int i = 0; i < 4; i++) {
#pragma unroll
        for (int j = 0; j < 4; j++) {
            int col = n0 + wn * 64 + j * 16 + l16;
            float bv = bf ? bf2f(((const unsigned short*)bias)[col])
                          : ((const float*)bias)[col];
#pragma unroll
            for (int r = 0; r < 4; r++) {
                int row = m0 + wm * 64 + i * 16 + quad * 4 + r;
                if (row < M) {
                    float v = acc[i][j][r] + bv;
                    if (relu) v = fmaxf(v, 0.0f);
                    C[(size_t)row * 256 + col] = f2bf(v);
                    if (C8) {
                        int pk = __builtin_amdgcn_cvt_pk_fp8_f32(v, v, 0, false);
                        C8[(size_t)row * 256 + col] = (unsigned char)(pk & 0xff);
                    }
                }
            }
        }
    }
}

// ---------- classifier head ------------------------------------------------
__global__ void cls_kernel(const unsigned short* __restrict__ h2,
                           const int* __restrict__ aidx,
                           const void* __restrict__ Wc,
                           const void* __restrict__ bc,
                           const int* __restrict__ flagp,
                           void* __restrict__ out) {
    int lin = blockIdx.x * blockDim.x + threadIdx.x;
    int a = lin >> 6, lane = lin & 63;
    if (a >= N_ASPECTS) return;
    int bf = *flagp;
    int node = aidx[a];
    uint2 v = *reinterpret_cast<const uint2*>(h2 + (size_t)node * 256 + lane * 4);
    float hv[4] = {bflo(v.x), bfhi(v.x), bflo(v.y), bfhi(v.y)};
    float a0 = 0.f, a1 = 0.f, a2 = 0.f;
#pragma unroll
    for (int r = 0; r < 4; r++) {
        int k = lane * 4 + r;
        float w0 = bf ? bf2f(((const unsigned short*)Wc)[k * 3 + 0]) : ((const float*)Wc)[k * 3 + 0];
        float w1 = bf ? bf2f(((const unsigned short*)Wc)[k * 3 + 1]) : ((const float*)Wc)[k * 3 + 1];
        float w2 = bf ? bf2f(((const unsigned short*)Wc)[k * 3 + 2]) : ((const float*)Wc)[k * 3 + 2];
        a0 += hv[r] * w0;
        a1 += hv[r] * w1;
        a2 += hv[r] * w2;
    }
#pragma unroll
    for (int off = 32; off >= 1; off >>= 1) {
        a0 += __shfl_down(a0, off);
        a1 += __shfl_down(a1, off);
        a2 += __shfl_down(a2, off);
    }
    if (lane == 0) {
        float b0 = bf ? bf2f(((const unsigned short*)bc)[0]) : ((const float*)bc)[0];
        float b1 = bf ? bf2f(((const unsigned short*)bc)[1]) : ((const float*)bc)[1];
        float b2 = bf ? bf2f(((const unsigned short*)bc)[2]) : ((const float*)bc)[2];
        if (bf) {
            unsigned short* o = (unsigned short*)out;
            o[a * 3 + 0] = f2bf(a0 + b0);
            o[a * 3 + 1] = f2bf(a1 + b1);
            o[a * 3 + 2] = f2bf(a2 + b2);
        } else {
            float* o = (float*)out;
            o[a * 3 + 0] = a0 + b0;
            o[a * 3 + 1] = a1 + b1;
            o[a * 3 + 2] = a2 + b2;
        }
    }
}

extern "C" void kernel_launch(void* const* d_in, const int* in_sizes, int n_in,
                              void* d_out, int out_size, void* d_ws, size_t ws_size,
                              hipStream_t stream) {
    const void* x   = d_in[0];
    const void* Wt1 = d_in[1];
    const void* Ws1 = d_in[2];
    const void* b1  = d_in[3];
    const void* Wt2 = d_in[4];
    const void* Ws2 = d_in[5];
    const void* b2  = d_in[6];
    const void* Wc  = d_in[7];
    const void* bc  = d_in[8];
    const int* ei = (const int*)d_in[9];
    const int* et = (const int*)d_in[10];
    const int* ai = (const int*)d_in[11];

    char* ws = (char*)d_ws;
    size_t off = 0;
    auto alloc = [&](size_t bytes) {
        void* p = ws + off;
        off += (bytes + 255) & ~(size_t)255;
        return p;
    };
    int*            flag          = (int*)alloc(4);
    int*            bucket_cursor = (int*)alloc((size_t)NBUCK * 4);
    int*            offsets4      = (int*)alloc((size_t)(NT4 + 1) * 4);
    unsigned int*   breg          = (unsigned int*)alloc((size_t)NBUCK * BCAP * 4); // 3.2 MB
    unsigned short* perm          = (unsigned short*)alloc((size_t)N_EDGES * 2);
    unsigned short* xc            = (unsigned short*)alloc((size_t)N_NODES * IN_DIM * 2);
    unsigned int*   xc8           = (unsigned int*)alloc((size_t)N_NODES * IN_DIM);    // 2.6 MB fp8
    unsigned short* AG            = (unsigned short*)alloc((size_t)N_NODES * 4 * HID_DIM * 2);
    unsigned short* h             = (unsigned short*)alloc((size_t)N_NODES * HID_DIM * 2);
    unsigned char*  h8            = (unsigned char*)alloc((size_t)N_NODES * HID_DIM);  // 5.1 MB fp8
    unsigned short* h2            = (unsigned short*)alloc((size_t)N_NODES * HID_DIM * 2);
    unsigned short* WT1           = (unsigned short*)alloc((size_t)640 * 256 * 2);
    unsigned short* WT2           = (unsigned short*)alloc((size_t)1280 * 256 * 2);
    // total ~60 MB

    hipMemsetAsync(bucket_cursor, 0, (size_t)NBUCK * 4, stream);
    prepA_kernel<<<3421, 256, 0, stream>>>(x, Ws1, Wt1, Ws2, Wt2, ei, et,
                                           xc, xc8, WT1, WT2, bucket_cursor, breg, flag);
    bucketB_kernel<<<NBUCK, 256, 0, stream>>>(breg, bucket_cursor, perm, offsets4);

    // Layer 1 (fp8 gather on x; self-term X stays bf16)
    agg8_kernel<IN_DIM><<<4096, 256, 0, stream>>>(xc8, offsets4, perm, AG);
    gemm_kernel<IN_DIM><<<320, 256, 0, stream>>>(xc, AG, WT1, b1, flag, h, h8, N_NODES, 1);
    // Layer 2 (fp8 shadow emitted by gemm1's epilogue)
    agg8_kernel<HID_DIM><<<4096, 256, 0, stream>>>((const unsigned int*)h8, offsets4, perm, AG);
    gemm_kernel<HID_DIM><<<320, 256, 0, stream>>>(h, AG, WT2, b2, flag, h2, nullptr, N_NODES, 0);
    // Head
    cls_kernel<<<(N_ASPECTS * 64) / 256, 256, 0, stream>>>(h2, ai, Wc, bc, flag, d_out);
}